// Round 10
// baseline (177.571 us; speedup 1.0000x reference)
//
#include <hip/hip_runtime.h>
#include <hip/hip_bf16.h>

typedef unsigned int u32;
typedef unsigned short u16;
typedef unsigned char u8;

typedef float f32x16 __attribute__((ext_vector_type(16)));
typedef short bf16x8 __attribute__((ext_vector_type(8)));

// ---- workspace layout (bytes after 64B header) -----------------------------
// A1eff[9 off][2 mt][2 hi][32 lane][8 k] bf16 (stencil folded into W1^T) 18432B
// A1b  [2 mt][2 hi][32 lane][8 k]       bf16 (b1/16 replicated)          2048B
// WT2p [32 ch][80 k]  bf16  K-PERMUTED to match o1 register order        5120B
// WT3p [32 row][32 k] bf16  K-permuted to o2 order, M-permuted so lane
//                           (n,hh) ends with ch 8hh..8hh+7 contiguous    2048B
// B3   [16] f32                                                            64B
#define OFF_A1  0
#define OFF_A1B 18432
#define OFF_WT2 20480
#define OFF_WT3 25600
#define OFF_B3  27648
#define PREP_N  13840   // 9216 + 1024 + 2560 + 1024 + 16

__device__ __forceinline__ float bf2f(u16 h) {
  return __uint_as_float(((u32)h) << 16);
}
__device__ __forceinline__ u16 f2bf(float f) {  // RNE (prep only)
  u32 u = __float_as_uint(f);
  return (u16)((u + 0x7FFFu + ((u >> 16) & 1u)) >> 16);
}
// hot-path pack: single v_cvt_pk_bf16_f32 (RNE; verified R7)
__device__ __forceinline__ u32 pkbf(float a, float b) {
  u32 r;
  asm("v_cvt_pk_bf16_f32 %0, %1, %2" : "=v"(r) : "v"(a), "v"(b));
  return r;  // lo16 = bf16(a), hi16 = bf16(b)
}
__device__ __forceinline__ float rdv(const void* s, int i, bool bf) {
  return bf ? bf2f(((const u16*)s)[i]) : ((const float*)s)[i];
}

// ---------------------------------------------------------------------------
// Weight prep (probe folded in; verified R1-R9).
// K-permutation (layers 2,3): logical k-slot = 16s + 8hh + 2q + e must hold
// the channel resident in o{1,2}[4s+q] bf16-half e of a hh-half lane:
//   L2: c = 32*(s>>1) + 8*(2*(s&1)+(q>>1)) + 4*hh + 2*(q&1) + e
//   L3: c = 8*(2*s+(q>>1)) + 4*hh + 2*(q&1) + e
// M-permutation (layer 3): row r<16 holds output channel
//   cout(r) = (r&3) + 4*((r>>3)&1) + 8*((r>>2)&1)   (rows 16..31 zero)
// so lane (n,hh) reg e (e<8) = channel 8hh+e  -> contiguous 32B per lane.
// ---------------------------------------------------------------------------
__global__ void prep_weights(const void* __restrict__ w1, const void* __restrict__ b1,
                             const void* __restrict__ w2, const void* __restrict__ b2,
                             const void* __restrict__ w3, const void* __restrict__ b3,
                             u8* __restrict__ Wb) {
  __shared__ int sg;
  if (threadIdx.x == 0) sg = 0;
  __syncthreads();
  {
    const u16* w1h = (const u16*)w1;
    int g = 0;
#pragma unroll
    for (int k = 0; k < 8; ++k) {
      u16 h = w1h[threadIdx.x * 8 + k];
      int e = (h >> 7) & 0xFF;
      if (e >= 0xC0) g++;
    }
    if (g) atomicAdd(&sg, g);
  }
  __syncthreads();
  const bool bf = (sg == 0);

  int i = blockIdx.x * 256 + threadIdx.x;
  if (i >= PREP_N) return;
  if (i < 9216) {                       // A1eff
    int off = i >> 10, rem = i & 1023;
    int mt = rem >> 9, hi = (rem >> 8) & 1, l = (rem >> 3) & 31, k8 = i & 7;
    int ch = mt * 32 + l, k = hi * 8 + k8;
    int oi = off / 3, oj = off % 3;
    const float axv[3] = {1.f, 2.f, 1.f};
    const float bxv[3] = {-1.f, 0.f, 1.f};
    float ci  = (oi == 1 && oj == 1) ? 1.f : 0.f;
    float dxv = axv[oi] * bxv[oj] * 0.125f;
    float dyv = axv[oj] * bxv[oi] * 0.125f;
    float v = ci  * rdv(w1, (3 * k + 0) * 64 + ch, bf)
            + dxv * rdv(w1, (3 * k + 1) * 64 + ch, bf)
            + dyv * rdv(w1, (3 * k + 2) * 64 + ch, bf);
    ((u16*)(Wb + OFF_A1))[i] = f2bf(v);
  } else if (i < 10240) {               // A1b: b1/16 in every k slot
    int j = i - 9216;
    int mt = j >> 9, l = (j >> 3) & 31;
    ((u16*)(Wb + OFF_A1B))[j] = f2bf(rdv(b1, mt * 32 + l, bf) * 0.0625f);
  } else if (i < 12800) {               // WT2p (K-permuted)
    int j = i - 10240, n = j / 80, k = j - n * 80;
    float v;
    if (k < 64) {
      int s = k >> 4, hh = (k >> 3) & 1, q = (k & 7) >> 1, e = k & 1;
      int c = 32 * (s >> 1) + 8 * (2 * (s & 1) + (q >> 1)) + 4 * hh + 2 * (q & 1) + e;
      v = rdv(w2, c * 32 + n, bf);
    } else {
      v = (k == 64) ? rdv(b2, n, bf) : 0.0f;
    }
    ((u16*)(Wb + OFF_WT2))[j] = f2bf(v);
  } else if (i < 13824) {               // WT3p (K- and M-permuted)
    int j = i - 12800, n = j >> 5, k = j & 31;
    float v = 0.0f;
    if (n < 16) {
      int cout = (n & 3) + 4 * ((n >> 3) & 1) + 8 * ((n >> 2) & 1);
      int s = k >> 4, hh = (k >> 3) & 1, q = (k & 7) >> 1, e = k & 1;
      int cin = 8 * (2 * s + (q >> 1)) + 4 * hh + 2 * (q & 1) + e;
      v = rdv(w3, cin * 16 + cout, bf);
    }
    ((u16*)(Wb + OFF_WT3))[j] = f2bf(v);
  } else {                              // B3 f32
    int j = i - 13824;
    ((float*)(Wb + OFF_B3))[j] = rdv(b3, j, bf);
  }
}

// ---------------------------------------------------------------------------
// Main kernel
// ---------------------------------------------------------------------------
// tanh(x) = 1 - 2/(e^{2x}+1);  e^{2x} = 2^{x * 2/ln2}  (verified R7)
__device__ __forceinline__ float fast_tanh(float x) {
  float e = __builtin_amdgcn_exp2f(x * 2.8853900817779268f);
  float r = __builtin_amdgcn_rcpf(e + 1.0f);
  return fmaf(-2.0f, r, 1.0f);
}

union U4 { uint4 q; u32 u[4]; bf16x8 h; float4 f; };

__device__ __forceinline__ void wave_lds_fence() {
  __builtin_amdgcn_wave_barrier();
  __asm__ __volatile__("s_waitcnt lgkmcnt(0)" ::: "memory");
  __builtin_amdgcn_wave_barrier();
}

#define MFMA(a, b, c) __builtin_amdgcn_mfma_f32_32x32x16_bf16((a), (b), (c), 0, 0, 0)

// LDS: xs[4 rows][258 cols][16 ch bf16] (stride 8256B, halo cols 0/257 zero)
//    + scratch[4 waves][2 bufs][32 px][80B]  (DOUBLE-BUFFERED, R10).
// R10: software-pipelined epilogue. Tile t's dx is written to buf[t&1] and
// consumed in iteration t+1: the ds_read issues BEFORE layer-1's ~600-cyc
// MFMA chain, the fma/stores land after it, and the per-tile fence now only
// orders writes that completed a full tile ago (1 fence/tile, was 2; no
// naked ~100cyc read-return wait). 53504B = R0's size -> 3 blk/CU verified.
// 4 blk/CU remains closed (R1/R3/R5: L2-residency thrash, +150MB FETCH).
#define XS_STRIDE 8256
#define SCR_OFF   33024
#define SCR_WAVE  5120
#define SCR_BUF   2560
#define LDS_TOTAL 53504

template <bool BF16>
__device__ __forceinline__ void nca_body(const void* __restrict__ xv,
                                         const u8* __restrict__ Wb,
                                         const void* __restrict__ maskv, int mw,
                                         void* __restrict__ outv,
                                         u8* __restrict__ xs) {
  const int tid = threadIdx.x;
  const int l   = tid & 63;
  const int wid = tid >> 6;
  const int l31 = l & 31;
  const int hi  = l >> 5;
  const int img   = blockIdx.x >> 7;
  const int r0    = (blockIdx.x & 127) << 1;      // first of 2 output rows

  // ---- stage x rows r0-1 .. r0+2 into LDS as bf16 (zero halo) -------------
  if (tid < 8) {        // halo cols 0 and 257, 4 rows
    int rr = tid >> 1, side = tid & 1;
    uint4 z = make_uint4(0, 0, 0, 0);
    uint4* d = (uint4*)(xs + rr * XS_STRIDE + (side ? 257 : 0) * 32);
    d[0] = z; d[1] = z;
  }
#pragma unroll
  for (int rr = 0; rr < 4; ++rr) {
    int hr = r0 - 1 + rr;
    bool valid = (hr >= 0) && (hr <= 255);
    if (BF16) {
      const u16* src = (const u16*)xv + ((size_t)(img * 256 + hr) << 12);
#pragma unroll
      for (int s = 0; s < 2; ++s) {
        int c = s * 256 + tid;        // 16B chunk: col c>>1, half c&1
        uint4 v = make_uint4(0, 0, 0, 0);
        if (valid) v = *(const uint4*)(src + c * 8);
        *(uint4*)(xs + rr * XS_STRIDE + ((c >> 1) + 1) * 32 + (c & 1) * 16) = v;
      }
    } else {
      const float* src = (const float*)xv + ((size_t)(img * 256 + hr) << 12);
#pragma unroll
      for (int k = 0; k < 4; ++k) {
        int q = k * 256 + tid;        // float4 #q: col q>>2, ch-quad q&3
        uint2 w = make_uint2(0, 0);
        if (valid) {
          float4 v = *(const float4*)(src + q * 4);
          w.x = pkbf(v.x, v.y); w.y = pkbf(v.z, v.w);
        }
        *(uint2*)(xs + rr * XS_STRIDE + ((q >> 2) + 1) * 32 + (q & 3) * 8) = w;
      }
    }
  }
  __syncthreads();

  const int sr      = wid >> 1;                 // wave's top staged row
  const int colbase = (wid & 1) * 128;          // wave's column half
  const int gr      = img * 256 + r0 + sr;      // global image row
  const int growpix = gr << 8;                  // pixel index of row start

  // ---- hoisted invariants -------------------------------------------------
  bf16x8 A1b[2];
#pragma unroll
  for (int mt = 0; mt < 2; ++mt) {
    U4 t; t.q = *(const uint4*)(Wb + OFF_A1B + ((mt * 2 + hi) * 32 + l31) * 16);
    A1b[mt] = t.h;
  }
  U4 ones; ones.u[0] = ones.u[1] = ones.u[2] = ones.u[3] = 0x3F803F80u;
  const float* B3f = (const float*)(Wb + OFF_B3);
  float4 b3lo = *(const float4*)(B3f + 8 * hi);       // ch 8hi+0..3
  float4 b3hi4 = *(const float4*)(B3f + 8 * hi + 4);  // ch 8hi+4..7
  u8* scr = xs + SCR_OFF + wid * SCR_WAVE;

  // tile-invariant layer-2/3 weight fragments in registers (verified R8)
  bf16x8 A2h[5], A3h[2];
#pragma unroll
  for (int s = 0; s < 5; ++s) {
    U4 t; t.q = *(const uint4*)(Wb + OFF_WT2 + l31 * 160 + s * 32 + hi * 16);
    A2h[s] = t.h;
  }
#pragma unroll
  for (int s = 0; s < 2; ++s) {
    U4 t; t.q = *(const uint4*)(Wb + OFF_WT3 + l31 * 64 + s * 32 + hi * 16);
    A3h[s] = t.h;
  }
  U4 bbf; bbf.u[0] = hi ? 0u : 0x00003F80u; bbf.u[1] = 0; bbf.u[2] = 0; bbf.u[3] = 0;

  // epilogue lane geometry (tile-invariant parts)
  const int ep_px = l >> 2;                     // 0..15 (P adds 16)
  const int ep_qd = l & 3;                      // channel quad

  // pipelined epilogue state (from previous tile)
  float pm1 = 0.f, pm2 = 0.f;
  int pe1 = 0, pe2 = 0;
  uint2 pxu1 = {0, 0}, pxu2 = {0, 0};
  float4 pxc1 = {0,0,0,0}, pxc2 = {0,0,0,0};

  // ---- 4 tiles of 32 px each, epilogue pipelined one tile back ------------
#pragma unroll
  for (int t = 0; t < 4; ++t) {
    const int cb = colbase + t * 32;

    // ---- prefetch epilogue x + mask for THIS tile (consumed at t+1) -------
    const int gpx1 = growpix + cb + ep_px;        // P=0 pixel
    const int gpx2 = gpx1 + 16;                   // P=1 pixel
    const int e1 = gpx1 * 16 + ep_qd * 4;
    const int e2 = gpx2 * 16 + ep_qd * 4;
    bool ms1, ms2;
    if (mw == 1)      { ms1 = ((const u8*)maskv)[gpx1] != 0;  ms2 = ((const u8*)maskv)[gpx2] != 0; }
    else if (mw == 2) { ms1 = ((const u16*)maskv)[gpx1] != 0; ms2 = ((const u16*)maskv)[gpx2] != 0; }
    else              { ms1 = ((const u32*)maskv)[gpx1] != 0; ms2 = ((const u32*)maskv)[gpx2] != 0; }
    const float mf1 = ms1 ? 1.0f : 0.0f;
    const float mf2 = ms2 ? 1.0f : 0.0f;
    uint2 xu1 = {0, 0}, xu2 = {0, 0};
    float4 xc1 = {0,0,0,0}, xc2 = {0,0,0,0};
    if (BF16) {
      xu1 = *(const uint2*)((const u16*)xv + e1);
      xu2 = *(const uint2*)((const u16*)xv + e2);
    } else {
      xc1 = *(const float4*)((const float*)xv + e1);
      xc2 = *(const float4*)((const float*)xv + e2);
    }

    // ---- issue previous tile's dx reads (buf written a full tile ago; -----
    // consumed after layer 1 so the read-return hides under the MFMA chain)
    float4 dx1 = {0,0,0,0}, dx2 = {0,0,0,0};
    if (t > 0) {
      const u8* pb = scr + ((t - 1) & 1) * SCR_BUF;
      dx1 = *(const float4*)(pb + ep_px * 80 + ep_qd * 16);
      dx2 = *(const float4*)(pb + (16 + ep_px) * 80 + ep_qd * 16);
    }

    // ---- layer 1: 2 bias MFMA + 9 shifted-offset MFMAs per M-tile ---------
    f32x16 c0 = {0,0,0,0,0,0,0,0,0,0,0,0,0,0,0,0};
    f32x16 c1 = {0,0,0,0,0,0,0,0,0,0,0,0,0,0,0,0};
    c0 = MFMA(A1b[0], ones.h, c0);
    c1 = MFMA(A1b[1], ones.h, c1);
#pragma unroll
    for (int off = 0; off < 9; ++off) {
      const int oi = off / 3, oj = off % 3;
      U4 bx; bx.q = *(const uint4*)(xs + (sr + oi) * XS_STRIDE +
                                    (cb + l31 + oj) * 32 + hi * 16);
      U4 a0; a0.q = *(const uint4*)(Wb + OFF_A1 + (((off * 2 + 0) * 2 + hi) * 32 + l31) * 16);
      U4 a1; a1.q = *(const uint4*)(Wb + OFF_A1 + (((off * 2 + 1) * 2 + hi) * 32 + l31) * 16);
      c0 = MFMA(a0.h, bx.h, c0);
      c1 = MFMA(a1.h, bx.h, c1);
    }

    // ---- epilogue of tile t-1: prefetched x/mask + pipelined dx -----------
    if (t > 0) {
      if (BF16) {
        float x10 = bf2f((u16)(pxu1.x & 0xFFFF)), x11 = bf2f((u16)(pxu1.x >> 16));
        float x12 = bf2f((u16)(pxu1.y & 0xFFFF)), x13 = bf2f((u16)(pxu1.y >> 16));
        float x20 = bf2f((u16)(pxu2.x & 0xFFFF)), x21 = bf2f((u16)(pxu2.x >> 16));
        float x22 = bf2f((u16)(pxu2.y & 0xFFFF)), x23 = bf2f((u16)(pxu2.y >> 16));
        uint2 wa, wb;
        wa.x = pkbf(fmaf(dx1.x, pm1, x10), fmaf(dx1.y, pm1, x11));
        wa.y = pkbf(fmaf(dx1.z, pm1, x12), fmaf(dx1.w, pm1, x13));
        wb.x = pkbf(fmaf(dx2.x, pm2, x20), fmaf(dx2.y, pm2, x21));
        wb.y = pkbf(fmaf(dx2.z, pm2, x22), fmaf(dx2.w, pm2, x23));
        *(uint2*)((u16*)outv + pe1) = wa;
        *(uint2*)((u16*)outv + pe2) = wb;
      } else {
        float4 oa, ob;
        oa.x = fmaf(dx1.x, pm1, pxc1.x); oa.y = fmaf(dx1.y, pm1, pxc1.y);
        oa.z = fmaf(dx1.z, pm1, pxc1.z); oa.w = fmaf(dx1.w, pm1, pxc1.w);
        ob.x = fmaf(dx2.x, pm2, pxc2.x); ob.y = fmaf(dx2.y, pm2, pxc2.y);
        ob.z = fmaf(dx2.z, pm2, pxc2.z); ob.w = fmaf(dx2.w, pm2, pxc2.w);
        *(float4*)((float*)outv + pe1) = oa;
        *(float4*)((float*)outv + pe2) = ob;
      }
    }

    // tanh + pack: o1[mt*8+g*2+pp] = ch(32mt+8g+4hi+2pp, +1)
    u32 o1[16];
#pragma unroll
    for (int g = 0; g < 4; ++g)
#pragma unroll
      for (int pp = 0; pp < 2; ++pp) {
        o1[g * 2 + pp]     = pkbf(fast_tanh(c0[g * 4 + 2 * pp]), fast_tanh(c0[g * 4 + 2 * pp + 1]));
        o1[8 + g * 2 + pp] = pkbf(fast_tanh(c1[g * 4 + 2 * pp]), fast_tanh(c1[g * 4 + 2 * pp + 1]));
      }

    // ---- layer 2: B-frag = o1[4s..4s+3] (hoisted K-permuted weights) ------
    f32x16 c2 = {0,0,0,0,0,0,0,0,0,0,0,0,0,0,0,0};
#pragma unroll
    for (int s = 0; s < 4; ++s) {
      U4 bfr; bfr.u[0] = o1[4*s]; bfr.u[1] = o1[4*s+1]; bfr.u[2] = o1[4*s+2]; bfr.u[3] = o1[4*s+3];
      c2 = MFMA(A2h[s], bfr.h, c2);
    }
    c2 = MFMA(A2h[4], bbf.h, c2);
    u32 o2[8];
#pragma unroll
    for (int g = 0; g < 4; ++g)
#pragma unroll
      for (int pp = 0; pp < 2; ++pp)
        o2[g * 2 + pp] = pkbf(fast_tanh(c2[g * 4 + 2 * pp]), fast_tanh(c2[g * 4 + 2 * pp + 1]));

    // ---- layer 3: B-frag = o2[4s..4s+3]; hoisted M-permuted weights -------
    f32x16 c3 = {0,0,0,0,0,0,0,0,0,0,0,0,0,0,0,0};
#pragma unroll
    for (int s = 0; s < 2; ++s) {
      U4 bfr; bfr.u[0] = o2[4*s]; bfr.u[1] = o2[4*s+1]; bfr.u[2] = o2[4*s+2]; bfr.u[3] = o2[4*s+3];
      c3 = MFMA(A3h[s], bfr.h, c3);
    }

    // dx + b3 -> this tile's scratch buffer (consumed next iteration)
    U4 w0, w1;
    w0.f.x = c3[0] + b3lo.x;  w0.f.y = c3[1] + b3lo.y;
    w0.f.z = c3[2] + b3lo.z;  w0.f.w = c3[3] + b3lo.w;
    w1.f.x = c3[4] + b3hi4.x; w1.f.y = c3[5] + b3hi4.y;
    w1.f.z = c3[6] + b3hi4.z; w1.f.w = c3[7] + b3hi4.w;
    u8* sa = scr + (t & 1) * SCR_BUF + l31 * 80 + hi * 32;
    *(float4*)(sa) = w0.f;
    *(float4*)(sa + 16) = w1.f;
    wave_lds_fence();   // single fence: orders this write vs next iter's read
                        // AND last iter's reads vs the overwrite 2 tiles out

    // save epilogue state for next iteration
    pm1 = mf1; pm2 = mf2; pe1 = e1; pe2 = e2;
    pxu1 = xu1; pxu2 = xu2; pxc1 = xc1; pxc2 = xc2;
  }

  // ---- drain: epilogue of tile 3 (buf 1; fence above guarantees writes) ---
  {
    const u8* pb = scr + (3 & 1) * SCR_BUF;
    float4 dx1 = *(const float4*)(pb + ep_px * 80 + ep_qd * 16);
    float4 dx2 = *(const float4*)(pb + (16 + ep_px) * 80 + ep_qd * 16);
    if (BF16) {
      float x10 = bf2f((u16)(pxu1.x & 0xFFFF)), x11 = bf2f((u16)(pxu1.x >> 16));
      float x12 = bf2f((u16)(pxu1.y & 0xFFFF)), x13 = bf2f((u16)(pxu1.y >> 16));
      float x20 = bf2f((u16)(pxu2.x & 0xFFFF)), x21 = bf2f((u16)(pxu2.x >> 16));
      float x22 = bf2f((u16)(pxu2.y & 0xFFFF)), x23 = bf2f((u16)(pxu2.y >> 16));
      uint2 wa, wb;
      wa.x = pkbf(fmaf(dx1.x, pm1, x10), fmaf(dx1.y, pm1, x11));
      wa.y = pkbf(fmaf(dx1.z, pm1, x12), fmaf(dx1.w, pm1, x13));
      wb.x = pkbf(fmaf(dx2.x, pm2, x20), fmaf(dx2.y, pm2, x21));
      wb.y = pkbf(fmaf(dx2.z, pm2, x22), fmaf(dx2.w, pm2, x23));
      *(uint2*)((u16*)outv + pe1) = wa;
      *(uint2*)((u16*)outv + pe2) = wb;
    } else {
      float4 oa, ob;
      oa.x = fmaf(dx1.x, pm1, pxc1.x); oa.y = fmaf(dx1.y, pm1, pxc1.y);
      oa.z = fmaf(dx1.z, pm1, pxc1.z); oa.w = fmaf(dx1.w, pm1, pxc1.w);
      ob.x = fmaf(dx2.x, pm2, pxc2.x); ob.y = fmaf(dx2.y, pm2, pxc2.y);
      ob.z = fmaf(dx2.z, pm2, pxc2.z); ob.w = fmaf(dx2.w, pm2, pxc2.w);
      *(float4*)((float*)outv + pe1) = oa;
      *(float4*)((float*)outv + pe2) = ob;
    }
  }
}

__global__ __launch_bounds__(256, 3) void nca_main(const void* __restrict__ xv,
                                                   const u16* __restrict__ w1h,
                                                   const u8* __restrict__ Wb,
                                                   const void* __restrict__ maskv,
                                                   void* __restrict__ outv) {
  __shared__ __align__(16) u8 smem[LDS_TOTAL];
  __shared__ int sg, su8, sbf;
  if (threadIdx.x == 0) { sg = 0; su8 = 0; sbf = 0; }
  __syncthreads();
  {  // in-block probe (verified R1-R9; L2-hot reads, ~no cost)
    int g = 0;
#pragma unroll
    for (int k = 0; k < 8; ++k) {
      u16 h = w1h[threadIdx.x * 8 + k];
      int e = (h >> 7) & 0xFF;
      if (e >= 0xC0) g++;
    }
    if (g) atomicAdd(&sg, g);
    u32 w = ((const u32*)maskv)[threadIdx.x];
    bool bytes01 = ((w & 0xFEFEFEFEu) == 0u);
    int bsum = (int)(w & 1u) + (int)((w >> 8) & 1u) +
               (int)((w >> 16) & 1u) + (int)((w >> 24) & 1u);
    if (bytes01 && bsum >= 2) atomicAdd(&su8, 1);
    if (w == 0x3F803F80u || w == 0x00003F80u) atomicAdd(&sbf, 1);
  }
  __syncthreads();
  const bool isbf = (sg == 0);                  // wave-uniform
  const int mw = (su8 > 0) ? 1 : ((sbf > 0) ? 2 : 4);

  // NO XCD swizzle (neutral-at-best per R1/R3 traffic accounting).
  if (isbf) nca_body<true>(xv, Wb, maskv, mw, outv, smem);
  else      nca_body<false>(xv, Wb, maskv, mw, outv, smem);
}

// ---------------------------------------------------------------------------
extern "C" void kernel_launch(void* const* d_in, const int* in_sizes, int n_in,
                              void* d_out, int out_size, void* d_ws, size_t ws_size,
                              hipStream_t stream) {
  // d_in: 0=x, 1=w1, 2=b1, 3=w2, 4=b2, 5=w3, 6=b3, 7=update_mask
  u8* Wb = (u8*)d_ws + 64;

  prep_weights<<<(PREP_N + 255) / 256, 256, 0, stream>>>(
      d_in[1], d_in[2], d_in[3], d_in[4], d_in[5], d_in[6], Wb);

  const int pixels = in_sizes[7];            // B*H*W = 1048576
  const int blocks = pixels / 512;           // 2048: two 256-px rows per block
  nca_main<<<blocks, 256, 0, stream>>>(d_in[0], (const u16*)d_in[1], Wb,
                                       d_in[7], d_out);
}